// Round 1
// baseline (482.037 us; speedup 1.0000x reference)
//
#include <hip/hip_runtime.h>

// RecoveryODENetwork: fused x_model + GRU-ODE scan + output head, single kernel.
// B=2048, T=256, I=64, XH=128, G=Hd=64, O=24.
// Layout strategy: transposed matmuls Dt = W * h^T with MFMA 16x16x32 bf16.
//   A-frag (weights, const): lane holds A[row=l&15][k=8*(l>>4)+e]
//   B-frag (activations):    lane holds B[k=8*(l>>4)+e][col=l&15]   (col = batch)
//   D:                       lane holds D[row=4*(l>>4)+j][col=l&15] (m89-verified)
// Block = 16 batch rows, 4 waves; gate-dim tiles split across waves; 3 barriers/step.
// Recurrent operands (h, r*h, h') stored in LDS as bf16 hi+lo splits for accuracy.

#define T_STEPS 256

typedef short bf16x8 __attribute__((ext_vector_type(8)));
typedef short short4v __attribute__((ext_vector_type(4)));
typedef float f32x4 __attribute__((ext_vector_type(4)));

#define MFMA(a, b, c) __builtin_amdgcn_mfma_f32_16x16x32_bf16((a), (b), (c), 0, 0, 0)

__device__ __forceinline__ short f2bf(float f) {
  unsigned u = __builtin_bit_cast(unsigned, f);
  return (short)((u + 0x7FFFu + ((u >> 16) & 1u)) >> 16);  // RNE
}
__device__ __forceinline__ float bf2f(short s) {
  return __builtin_bit_cast(float, ((unsigned)(unsigned short)s) << 16);
}

__device__ __forceinline__ f32x4 sigm4(f32x4 x) {
  f32x4 r;
#pragma unroll
  for (int j = 0; j < 4; ++j) {
    float e = __builtin_amdgcn_exp2f(-1.442695041f * x[j]);
    r[j] = __builtin_amdgcn_rcpf(1.f + e);
  }
  return r;
}
__device__ __forceinline__ f32x4 tanh4(f32x4 x) {
  f32x4 r;
#pragma unroll
  for (int j = 0; j < 4; ++j) {
    float xx = fmaxf(fminf(x[j], 30.f), -30.f);
    float e = __builtin_amdgcn_exp2f(-2.885390082f * xx);  // e^{-2x}
    r[j] = (1.f - e) * __builtin_amdgcn_rcpf(1.f + e);
  }
  return r;
}
__device__ __forceinline__ short4v cvt4(f32x4 v) {
  short4v p;
#pragma unroll
  for (int j = 0; j < 4; ++j) p[j] = f2bf(v[j]);
  return p;
}
__device__ __forceinline__ void split4(f32x4 v, short4v& hi, short4v& lo) {
#pragma unroll
  for (int j = 0; j < 4; ++j) {
    short s = f2bf(v[j]);
    hi[j] = s;
    lo[j] = f2bf(v[j] - bf2f(s));
  }
}
// Load an A-fragment of weight matrix W (row-major [out][in] fp32): rows=tile, k=c0..c0+7
__device__ __forceinline__ bf16x8 wfrag(const float* __restrict__ W, int stride, int row, int c0) {
  const float* p = W + (size_t)row * stride + c0;
  float4 a = *(const float4*)p;
  float4 b = *(const float4*)(p + 4);
  bf16x8 r;
  r[0] = f2bf(a.x); r[1] = f2bf(a.y); r[2] = f2bf(a.z); r[3] = f2bf(a.w);
  r[4] = f2bf(b.x); r[5] = f2bf(b.y); r[6] = f2bf(b.z); r[7] = f2bf(b.w);
  return r;
}

// XOR swizzle (G4): kills 16-way bank conflict of stride-128B/256B column reads
__device__ __forceinline__ int swz64(int row, int off) { return row * 128 + (off ^ ((row & 7) << 4)); }
__device__ __forceinline__ int swzH(int row, int off)  { return row * 256 + (off ^ ((row & 7) << 4)); }

__global__ __launch_bounds__(256, 1) void odegru(
    const float* __restrict__ H,
    const float* __restrict__ W1, const float* __restrict__ b1,
    const float* __restrict__ W2, const float* __restrict__ b2,
    const float* __restrict__ Wor, const float* __restrict__ Woz, const float* __restrict__ Woh,
    const float* __restrict__ wih, const float* __restrict__ whhg,
    const float* __restrict__ bih, const float* __restrict__ bhh,
    const float* __restrict__ Wr, const float* __restrict__ br,
    float* __restrict__ out) {
  const int tid = threadIdx.x;
  const int w = tid >> 6;    // wave 0..3
  const int l = tid & 63;
  const int col = l & 15;    // batch column within tile
  const int g = l >> 4;      // lane group
  const int b0 = blockIdx.x << 4;

  __shared__ __align__(16) char sm[18432];
  char* HIDb = sm;            // [16][128] bf16 hidden of x_model (4096B)
  char* XGb  = sm + 4096;     // [16][64]  bf16 HH_t
  char* Hhi  = sm + 6144;     // h state hi
  char* Hlo  = sm + 8192;     // h state lo
  char* H2hi = sm + 10240;    // h' hi
  char* H2lo = sm + 12288;    // h' lo
  char* RHhi = sm + 14336;    // r*h hi
  char* RHlo = sm + 16384;    // r*h lo

  // zero h state (hi+lo)
  ((long long*)Hhi)[tid] = 0;
  ((long long*)Hlo)[tid] = 0;

  const int r16 = 16 * w + col;  // A-frag row base for this wave's tiles

  // ---- constant weight A-fragments (bf16) ----
  bf16x8 aW1_00 = wfrag(W1, 64, r16, 8 * g),        aW1_01 = wfrag(W1, 64, r16, 32 + 8 * g);
  bf16x8 aW1_10 = wfrag(W1, 64, 64 + r16, 8 * g),   aW1_11 = wfrag(W1, 64, 64 + r16, 32 + 8 * g);
  bf16x8 aW2_0 = wfrag(W2, 128, r16, 8 * g),        aW2_1 = wfrag(W2, 128, r16, 32 + 8 * g);
  bf16x8 aW2_2 = wfrag(W2, 128, r16, 64 + 8 * g),   aW2_3 = wfrag(W2, 128, r16, 96 + 8 * g);
  bf16x8 aR0 = wfrag(Wor, 64, r16, 8 * g),          aR1 = wfrag(Wor, 64, r16, 32 + 8 * g);
  bf16x8 aZ0 = wfrag(Woz, 64, r16, 8 * g),          aZ1 = wfrag(Woz, 64, r16, 32 + 8 * g);
  bf16x8 aU0 = wfrag(Woh, 64, r16, 8 * g),          aU1 = wfrag(Woh, 64, r16, 32 + 8 * g);
  bf16x8 aIR0 = wfrag(wih, 64, r16, 8 * g),         aIR1 = wfrag(wih, 64, r16, 32 + 8 * g);
  bf16x8 aIZ0 = wfrag(wih, 64, 64 + r16, 8 * g),    aIZ1 = wfrag(wih, 64, 64 + r16, 32 + 8 * g);
  bf16x8 aIN0 = wfrag(wih, 64, 128 + r16, 8 * g),   aIN1 = wfrag(wih, 64, 128 + r16, 32 + 8 * g);
  bf16x8 aHR0 = wfrag(whhg, 64, r16, 8 * g),        aHR1 = wfrag(whhg, 64, r16, 32 + 8 * g);
  bf16x8 aHZ0 = wfrag(whhg, 64, 64 + r16, 8 * g),   aHZ1 = wfrag(whhg, 64, 64 + r16, 32 + 8 * g);
  bf16x8 aHN0 = wfrag(whhg, 64, 128 + r16, 8 * g),  aHN1 = wfrag(whhg, 64, 128 + r16, 32 + 8 * g);
  const int wr_row = r16 > 23 ? 23 : r16;  // Wr has only 24 rows; clamp (extra rows unused)
  bf16x8 aWr0 = wfrag(Wr, 64, wr_row, 8 * g),       aWr1 = wfrag(Wr, 64, wr_row, 32 + 8 * g);

  // ---- per-lane bias fragments (D rows = 16w + 4g + j) ----
  const int row4 = 16 * w + 4 * g;
  f32x4 bsr, bsz, bin_, bhn, b1a, b1b, b2w, brw;
#pragma unroll
  for (int j = 0; j < 4; ++j) {
    bsr[j] = bih[row4 + j] + bhh[row4 + j];
    bsz[j] = bih[64 + row4 + j] + bhh[64 + row4 + j];
    bin_[j] = bih[128 + row4 + j];
    bhn[j] = bhh[128 + row4 + j];
    b1a[j] = b1[row4 + j];
    b1b[j] = b1[64 + row4 + j];
    b2w[j] = b2[row4 + j];
    int o = row4 + j;
    brw[j] = br[o > 23 ? 23 : o];
  }

  // precomputed swizzled LDS offsets
  const int sR0 = swz64(col, 16 * g);
  const int sR1 = swz64(col, 64 + 16 * g);
  const int sW  = swz64(col, row4 * 2);
  const int sHid0 = swzH(col, 16 * g);
  const int sHid1 = swzH(col, 64 + 16 * g);
  const int sHid2 = swzH(col, 128 + 16 * g);
  const int sHid3 = swzH(col, 192 + 16 * g);
  const int sHidW0 = swzH(col, row4 * 2);
  const int sHidW1 = swzH(col, (64 + row4) * 2);

  // x (raw H) B-fragment source: per-lane direct global loads, prefetched 1 step ahead
  const float* xp = H + ((size_t)(b0 + col) * T_STEPS) * 64 + 8 * g;
  float4 xa = *(const float4*)(xp);
  float4 xb = *(const float4*)(xp + 4);
  float4 xc = *(const float4*)(xp + 32);
  float4 xd = *(const float4*)(xp + 36);

  float* outp = out + ((size_t)(b0 + col) * T_STEPS) * 24 + row4;

  f32x4 hreg = {0.f, 0.f, 0.f, 0.f};  // h^T[row4+j][col] in fp32
  __syncthreads();

  for (int t = 0; t < T_STEPS; ++t) {
    // ================= P0 =================
    bf16x8 xB0, xB1;
    xB0[0] = f2bf(xa.x); xB0[1] = f2bf(xa.y); xB0[2] = f2bf(xa.z); xB0[3] = f2bf(xa.w);
    xB0[4] = f2bf(xb.x); xB0[5] = f2bf(xb.y); xB0[6] = f2bf(xb.z); xB0[7] = f2bf(xb.w);
    xB1[0] = f2bf(xc.x); xB1[1] = f2bf(xc.y); xB1[2] = f2bf(xc.z); xB1[3] = f2bf(xc.w);
    xB1[4] = f2bf(xd.x); xB1[5] = f2bf(xd.y); xB1[6] = f2bf(xd.z); xB1[7] = f2bf(xd.w);
    if (t + 1 < T_STEPS) {  // prefetch x_{t+1}
      xp += 64;
      xa = *(const float4*)(xp);      xb = *(const float4*)(xp + 4);
      xc = *(const float4*)(xp + 32); xd = *(const float4*)(xp + 36);
    }

    bf16x8 hB0h = *(const bf16x8*)(Hhi + sR0);
    bf16x8 hB1h = *(const bf16x8*)(Hhi + sR1);
    bf16x8 hB0l = *(const bf16x8*)(Hlo + sR0);
    bf16x8 hB1l = *(const bf16x8*)(Hlo + sR1);

    // output head for step t-1 (h_lds currently holds hnew_{t-1})
    if (w < 2 && t > 0) {
      f32x4 a5 = brw;
      a5 = MFMA(aWr0, hB0h, a5); a5 = MFMA(aWr0, hB0l, a5);
      a5 = MFMA(aWr1, hB1h, a5); a5 = MFMA(aWr1, hB1l, a5);
      if (w == 0 || g < 2) { outp[0] = a5[0]; outp[1] = a5[1]; outp[2] = a5[2]; outp[3] = a5[3]; }
      outp += 24;
    }

    // x_model stage 1: hid = ReLU(W1 x^T + b1)  (this wave: hid rows 16w.., 64+16w..)
    f32x4 hid0 = b1a;
    hid0 = MFMA(aW1_00, xB0, hid0); hid0 = MFMA(aW1_01, xB1, hid0);
    f32x4 hid1 = b1b;
    hid1 = MFMA(aW1_10, xB0, hid1); hid1 = MFMA(aW1_11, xB1, hid1);
#pragma unroll
    for (int j = 0; j < 4; ++j) { hid0[j] = fmaxf(hid0[j], 0.f); hid1[j] = fmaxf(hid1[j], 0.f); }
    *(short4v*)(HIDb + sHidW0) = cvt4(hid0);
    *(short4v*)(HIDb + sHidW1) = cvt4(hid1);

    // ODE gates r,z
    f32x4 rp = {0.f, 0.f, 0.f, 0.f};
    rp = MFMA(aR0, hB0h, rp); rp = MFMA(aR0, hB0l, rp);
    rp = MFMA(aR1, hB1h, rp); rp = MFMA(aR1, hB1l, rp);
    f32x4 zp = {0.f, 0.f, 0.f, 0.f};
    zp = MFMA(aZ0, hB0h, zp); zp = MFMA(aZ0, hB0l, zp);
    zp = MFMA(aZ1, hB1h, zp); zp = MFMA(aZ1, hB1l, zp);
    f32x4 rr = sigm4(rp);
    f32x4 zz = sigm4(zp);
    {
      short4v phi, plo; split4(rr * hreg, phi, plo);
      *(short4v*)(RHhi + sW) = phi;
      *(short4v*)(RHlo + sW) = plo;
    }
    __syncthreads();

    // ================= P1 =================
    bf16x8 rhB0h = *(const bf16x8*)(RHhi + sR0);
    bf16x8 rhB1h = *(const bf16x8*)(RHhi + sR1);
    bf16x8 rhB0l = *(const bf16x8*)(RHlo + sR0);
    bf16x8 rhB1l = *(const bf16x8*)(RHlo + sR1);
    bf16x8 hdB0 = *(const bf16x8*)(HIDb + sHid0);
    bf16x8 hdB1 = *(const bf16x8*)(HIDb + sHid1);
    bf16x8 hdB2 = *(const bf16x8*)(HIDb + sHid2);
    bf16x8 hdB3 = *(const bf16x8*)(HIDb + sHid3);

    f32x4 up = {0.f, 0.f, 0.f, 0.f};
    up = MFMA(aU0, rhB0h, up); up = MFMA(aU0, rhB0l, up);
    up = MFMA(aU1, rhB1h, up); up = MFMA(aU1, rhB1l, up);
    f32x4 uu = tanh4(up);
    f32x4 hp = hreg + (1.f - zz) * (uu - hreg);  // ODE Euler step (DT=1)
    {
      short4v phi, plo; split4(hp, phi, plo);
      *(short4v*)(H2hi + sW) = phi;
      *(short4v*)(H2lo + sW) = plo;
    }
    // x_model stage 2: HH_t = W2 hid^T + b2 (this wave: rows 16w..)
    f32x4 xg = b2w;
    xg = MFMA(aW2_0, hdB0, xg); xg = MFMA(aW2_1, hdB1, xg);
    xg = MFMA(aW2_2, hdB2, xg); xg = MFMA(aW2_3, hdB3, xg);
    *(short4v*)(XGb + sW) = cvt4(xg);
    __syncthreads();

    // ================= P2 =================
    bf16x8 xgB0 = *(const bf16x8*)(XGb + sR0);
    bf16x8 xgB1 = *(const bf16x8*)(XGb + sR1);
    bf16x8 h2B0h = *(const bf16x8*)(H2hi + sR0);
    bf16x8 h2B1h = *(const bf16x8*)(H2hi + sR1);
    bf16x8 h2B0l = *(const bf16x8*)(H2lo + sR0);
    bf16x8 h2B1l = *(const bf16x8*)(H2lo + sR1);

    f32x4 ir = bsr;
    ir = MFMA(aIR0, xgB0, ir); ir = MFMA(aIR1, xgB1, ir);
    f32x4 iz = bsz;
    iz = MFMA(aIZ0, xgB0, iz); iz = MFMA(aIZ1, xgB1, iz);
    f32x4 inn = bin_;
    inn = MFMA(aIN0, xgB0, inn); inn = MFMA(aIN1, xgB1, inn);
    f32x4 hr = {0.f, 0.f, 0.f, 0.f};
    hr = MFMA(aHR0, h2B0h, hr); hr = MFMA(aHR0, h2B0l, hr);
    hr = MFMA(aHR1, h2B1h, hr); hr = MFMA(aHR1, h2B1l, hr);
    f32x4 hz = {0.f, 0.f, 0.f, 0.f};
    hz = MFMA(aHZ0, h2B0h, hz); hz = MFMA(aHZ0, h2B0l, hz);
    hz = MFMA(aHZ1, h2B1h, hz); hz = MFMA(aHZ1, h2B1l, hz);
    f32x4 hn = bhn;
    hn = MFMA(aHN0, h2B0h, hn); hn = MFMA(aHN0, h2B0l, hn);
    hn = MFMA(aHN1, h2B1h, hn); hn = MFMA(aHN1, h2B1l, hn);

    f32x4 r2 = sigm4(ir + hr);
    f32x4 z2 = sigm4(iz + hz);
    f32x4 nn = tanh4(inn + r2 * hn);
    hreg = (1.f - z2) * nn + z2 * hp;  // GRU update; h_new
    {
      short4v phi, plo; split4(hreg, phi, plo);
      *(short4v*)(Hhi + sW) = phi;
      *(short4v*)(Hlo + sW) = plo;
    }
    __syncthreads();
  }

  // epilogue: output for t = T-1
  if (w < 2) {
    bf16x8 hB0h = *(const bf16x8*)(Hhi + sR0);
    bf16x8 hB1h = *(const bf16x8*)(Hhi + sR1);
    bf16x8 hB0l = *(const bf16x8*)(Hlo + sR0);
    bf16x8 hB1l = *(const bf16x8*)(Hlo + sR1);
    f32x4 a5 = brw;
    a5 = MFMA(aWr0, hB0h, a5); a5 = MFMA(aWr0, hB0l, a5);
    a5 = MFMA(aWr1, hB1h, a5); a5 = MFMA(aWr1, hB1l, a5);
    if (w == 0 || g < 2) { outp[0] = a5[0]; outp[1] = a5[1]; outp[2] = a5[2]; outp[3] = a5[3]; }
  }
}

extern "C" void kernel_launch(void* const* d_in, const int* in_sizes, int n_in,
                              void* d_out, int out_size, void* d_ws, size_t ws_size,
                              hipStream_t stream) {
  (void)in_sizes; (void)n_in; (void)d_ws; (void)ws_size; (void)out_size;
  const float* H   = (const float*)d_in[0];
  // d_in[1] = times (unused: delta_t == 1 -> exactly one Euler step per observation)
  const float* W1  = (const float*)d_in[2];
  const float* b1  = (const float*)d_in[3];
  const float* W2  = (const float*)d_in[4];
  const float* b2  = (const float*)d_in[5];
  const float* Whr = (const float*)d_in[6];
  const float* Whz = (const float*)d_in[7];
  const float* Whh = (const float*)d_in[8];
  const float* wih = (const float*)d_in[9];
  const float* whh = (const float*)d_in[10];
  const float* bih = (const float*)d_in[11];
  const float* bhh = (const float*)d_in[12];
  const float* Wr  = (const float*)d_in[13];
  const float* br  = (const float*)d_in[14];
  float* out = (float*)d_out;

  odegru<<<dim3(2048 / 16), dim3(256), 0, stream>>>(
      H, W1, b1, W2, b2, Whr, Whz, Whh, wih, whh, bih, bhh, Wr, br, out);
}

// Round 2
// 444.726 us; speedup vs baseline: 1.0839x; 1.0839x over previous
//
#include <hip/hip_runtime.h>
#include <hip/hip_bf16.h>

// RecoveryODENetwork: fused x_model + GRU-ODE scan + output head, single kernel.
// B=2048, T=256, I=64, XH=128, G=Hd=64, O=24.
// Transposed matmuls Dt = W * h^T with MFMA 16x16x32 bf16.
//   A-frag (weights, const): lane holds A[row=l&15][k=8*(l>>4)+e]
//   B-frag (activations):    lane holds B[k=8*(l>>4)+e][col=l&15]   (col = batch)
//   D:                       lane holds D[row=4*(l>>4)+j][col=l&15] (m89-verified)
// Block = 16 batch rows, 4 waves; gate-dim tiles split across waves; 3 barriers/step.
// Recurrent operands (h, r*h, h') stored in LDS as bf16 hi+lo splits for accuracy.
// R2 changes: (1) lite barriers (lgkmcnt-only: keep x-prefetch global loads in
// flight across barriers — T4 principle); (2) separate hi/lo MFMA accumulators
// (chain depth 4->2, 2-way ILP); (3) cheaper bf16 conversions (trunc-hi split).

#define T_STEPS 256

typedef short bf16x8 __attribute__((ext_vector_type(8)));
typedef short short4v __attribute__((ext_vector_type(4)));
typedef float f32x4 __attribute__((ext_vector_type(4)));

#define MFMA(a, b, c) __builtin_amdgcn_mfma_f32_16x16x32_bf16((a), (b), (c), 0, 0, 0)

// LDS-only barrier: orders ds ops across the block WITHOUT draining vmcnt —
// the x_{t+1} prefetch global loads stay in flight across all 3 step barriers.
__device__ __forceinline__ void barrier_lds() {
  asm volatile("s_waitcnt lgkmcnt(0)\n\ts_barrier" ::: "memory");
}

__device__ __forceinline__ short f2bf(float f) {
  __hip_bfloat16 b = __float2bfloat16(f);  // RNE; compiler may pack v_cvt_pk_bf16_f32
  return __builtin_bit_cast(short, b);
}
__device__ __forceinline__ float bf2f(short s) {
  return __builtin_bit_cast(float, ((unsigned)(unsigned short)s) << 16);
}

__device__ __forceinline__ f32x4 sigm4(f32x4 x) {
  f32x4 r;
#pragma unroll
  for (int j = 0; j < 4; ++j) {
    float e = __builtin_amdgcn_exp2f(-1.442695041f * x[j]);
    r[j] = __builtin_amdgcn_rcpf(1.f + e);
  }
  return r;
}
__device__ __forceinline__ f32x4 tanh4(f32x4 x) {
  f32x4 r;
#pragma unroll
  for (int j = 0; j < 4; ++j) {
    float xx = fmaxf(fminf(x[j], 30.f), -30.f);
    float e = __builtin_amdgcn_exp2f(-2.885390082f * xx);  // e^{-2x}
    r[j] = (1.f - e) * __builtin_amdgcn_rcpf(1.f + e);
  }
  return r;
}
__device__ __forceinline__ short4v cvt4(f32x4 v) {
  short4v p;
#pragma unroll
  for (int j = 0; j < 4; ++j) p[j] = f2bf(v[j]);
  return p;
}
// Exact-ish split: hi = truncate (1 op), lo = RNE(residual). Combined error ~2^-17 rel.
__device__ __forceinline__ void split4(f32x4 v, short4v& hi, short4v& lo) {
#pragma unroll
  for (int j = 0; j < 4; ++j) {
    unsigned u = __builtin_bit_cast(unsigned, v[j]);
    hi[j] = (short)(u >> 16);
    lo[j] = f2bf(v[j] - __builtin_bit_cast(float, u & 0xFFFF0000u));
  }
}
// Load an A-fragment of weight matrix W (row-major [out][in] fp32): rows=tile, k=c0..c0+7
__device__ __forceinline__ bf16x8 wfrag(const float* __restrict__ W, int stride, int row, int c0) {
  const float* p = W + (size_t)row * stride + c0;
  float4 a = *(const float4*)p;
  float4 b = *(const float4*)(p + 4);
  bf16x8 r;
  r[0] = f2bf(a.x); r[1] = f2bf(a.y); r[2] = f2bf(a.z); r[3] = f2bf(a.w);
  r[4] = f2bf(b.x); r[5] = f2bf(b.y); r[6] = f2bf(b.z); r[7] = f2bf(b.w);
  return r;
}

// XOR swizzle (G4): kills 16-way bank conflict of stride-128B/256B column reads
__device__ __forceinline__ int swz64(int row, int off) { return row * 128 + (off ^ ((row & 7) << 4)); }
__device__ __forceinline__ int swzH(int row, int off)  { return row * 256 + (off ^ ((row & 7) << 4)); }

__global__ __launch_bounds__(256, 1) void odegru(
    const float* __restrict__ H,
    const float* __restrict__ W1, const float* __restrict__ b1,
    const float* __restrict__ W2, const float* __restrict__ b2,
    const float* __restrict__ Wor, const float* __restrict__ Woz, const float* __restrict__ Woh,
    const float* __restrict__ wih, const float* __restrict__ whhg,
    const float* __restrict__ bih, const float* __restrict__ bhh,
    const float* __restrict__ Wr, const float* __restrict__ br,
    float* __restrict__ out) {
  const int tid = threadIdx.x;
  const int w = tid >> 6;    // wave 0..3
  const int l = tid & 63;
  const int col = l & 15;    // batch column within tile
  const int g = l >> 4;      // lane group
  const int b0 = blockIdx.x << 4;

  __shared__ __align__(16) char sm[18432];
  char* HIDb = sm;            // [16][128] bf16 hidden of x_model (4096B)
  char* XGb  = sm + 4096;     // [16][64]  bf16 HH_t
  char* Hhi  = sm + 6144;     // h state hi
  char* Hlo  = sm + 8192;     // h state lo
  char* H2hi = sm + 10240;    // h' hi
  char* H2lo = sm + 12288;    // h' lo
  char* RHhi = sm + 14336;    // r*h hi
  char* RHlo = sm + 16384;    // r*h lo

  // zero h state (hi+lo)
  ((long long*)Hhi)[tid] = 0;
  ((long long*)Hlo)[tid] = 0;

  const int r16 = 16 * w + col;  // A-frag row base for this wave's tiles

  // ---- constant weight A-fragments (bf16) ----
  bf16x8 aW1_00 = wfrag(W1, 64, r16, 8 * g),        aW1_01 = wfrag(W1, 64, r16, 32 + 8 * g);
  bf16x8 aW1_10 = wfrag(W1, 64, 64 + r16, 8 * g),   aW1_11 = wfrag(W1, 64, 64 + r16, 32 + 8 * g);
  bf16x8 aW2_0 = wfrag(W2, 128, r16, 8 * g),        aW2_1 = wfrag(W2, 128, r16, 32 + 8 * g);
  bf16x8 aW2_2 = wfrag(W2, 128, r16, 64 + 8 * g),   aW2_3 = wfrag(W2, 128, r16, 96 + 8 * g);
  bf16x8 aR0 = wfrag(Wor, 64, r16, 8 * g),          aR1 = wfrag(Wor, 64, r16, 32 + 8 * g);
  bf16x8 aZ0 = wfrag(Woz, 64, r16, 8 * g),          aZ1 = wfrag(Woz, 64, r16, 32 + 8 * g);
  bf16x8 aU0 = wfrag(Woh, 64, r16, 8 * g),          aU1 = wfrag(Woh, 64, r16, 32 + 8 * g);
  bf16x8 aIR0 = wfrag(wih, 64, r16, 8 * g),         aIR1 = wfrag(wih, 64, r16, 32 + 8 * g);
  bf16x8 aIZ0 = wfrag(wih, 64, 64 + r16, 8 * g),    aIZ1 = wfrag(wih, 64, 64 + r16, 32 + 8 * g);
  bf16x8 aIN0 = wfrag(wih, 64, 128 + r16, 8 * g),   aIN1 = wfrag(wih, 64, 128 + r16, 32 + 8 * g);
  bf16x8 aHR0 = wfrag(whhg, 64, r16, 8 * g),        aHR1 = wfrag(whhg, 64, r16, 32 + 8 * g);
  bf16x8 aHZ0 = wfrag(whhg, 64, 64 + r16, 8 * g),   aHZ1 = wfrag(whhg, 64, 64 + r16, 32 + 8 * g);
  bf16x8 aHN0 = wfrag(whhg, 64, 128 + r16, 8 * g),  aHN1 = wfrag(whhg, 64, 128 + r16, 32 + 8 * g);
  const int wr_row = r16 > 23 ? 23 : r16;  // Wr has only 24 rows; clamp (extra rows unused)
  bf16x8 aWr0 = wfrag(Wr, 64, wr_row, 8 * g),       aWr1 = wfrag(Wr, 64, wr_row, 32 + 8 * g);

  // ---- per-lane bias fragments (D rows = 16w + 4g + j) ----
  const int row4 = 16 * w + 4 * g;
  f32x4 bsr, bsz, bin_, bhn, b1a, b1b, b2w, brw;
#pragma unroll
  for (int j = 0; j < 4; ++j) {
    bsr[j] = bih[row4 + j] + bhh[row4 + j];
    bsz[j] = bih[64 + row4 + j] + bhh[64 + row4 + j];
    bin_[j] = bih[128 + row4 + j];
    bhn[j] = bhh[128 + row4 + j];
    b1a[j] = b1[row4 + j];
    b1b[j] = b1[64 + row4 + j];
    b2w[j] = b2[row4 + j];
    int o = row4 + j;
    brw[j] = br[o > 23 ? 23 : o];
  }

  // precomputed swizzled LDS offsets
  const int sR0 = swz64(col, 16 * g);
  const int sR1 = swz64(col, 64 + 16 * g);
  const int sW  = swz64(col, row4 * 2);
  const int sHid0 = swzH(col, 16 * g);
  const int sHid1 = swzH(col, 64 + 16 * g);
  const int sHid2 = swzH(col, 128 + 16 * g);
  const int sHid3 = swzH(col, 192 + 16 * g);
  const int sHidW0 = swzH(col, row4 * 2);
  const int sHidW1 = swzH(col, (64 + row4) * 2);

  // x (raw H) B-fragment source: per-lane direct global loads, prefetched 1 step ahead
  const float* xp = H + ((size_t)(b0 + col) * T_STEPS) * 64 + 8 * g;
  float4 xa = *(const float4*)(xp);
  float4 xb = *(const float4*)(xp + 4);
  float4 xc = *(const float4*)(xp + 32);
  float4 xd = *(const float4*)(xp + 36);

  float* outp = out + ((size_t)(b0 + col) * T_STEPS) * 24 + row4;

  f32x4 hreg = {0.f, 0.f, 0.f, 0.f};  // h^T[row4+j][col] in fp32
  barrier_lds();

  for (int t = 0; t < T_STEPS; ++t) {
    // ================= P0 =================
    bf16x8 xB0, xB1;
    xB0[0] = f2bf(xa.x); xB0[1] = f2bf(xa.y); xB0[2] = f2bf(xa.z); xB0[3] = f2bf(xa.w);
    xB0[4] = f2bf(xb.x); xB0[5] = f2bf(xb.y); xB0[6] = f2bf(xb.z); xB0[7] = f2bf(xb.w);
    xB1[0] = f2bf(xc.x); xB1[1] = f2bf(xc.y); xB1[2] = f2bf(xc.z); xB1[3] = f2bf(xc.w);
    xB1[4] = f2bf(xd.x); xB1[5] = f2bf(xd.y); xB1[6] = f2bf(xd.z); xB1[7] = f2bf(xd.w);
    if (t + 1 < T_STEPS) {  // prefetch x_{t+1}; stays in flight across lite barriers
      xp += 64;
      xa = *(const float4*)(xp);      xb = *(const float4*)(xp + 4);
      xc = *(const float4*)(xp + 32); xd = *(const float4*)(xp + 36);
    }

    bf16x8 hB0h = *(const bf16x8*)(Hhi + sR0);
    bf16x8 hB1h = *(const bf16x8*)(Hhi + sR1);
    bf16x8 hB0l = *(const bf16x8*)(Hlo + sR0);
    bf16x8 hB1l = *(const bf16x8*)(Hlo + sR1);

    // output head for step t-1 (h_lds currently holds hnew_{t-1})
    if (w < 2 && t > 0) {
      f32x4 a5 = brw, a5l = {0.f, 0.f, 0.f, 0.f};
      a5 = MFMA(aWr0, hB0h, a5);  a5 = MFMA(aWr1, hB1h, a5);
      a5l = MFMA(aWr0, hB0l, a5l); a5l = MFMA(aWr1, hB1l, a5l);
      a5 += a5l;
      if (w == 0 || g < 2) { outp[0] = a5[0]; outp[1] = a5[1]; outp[2] = a5[2]; outp[3] = a5[3]; }
      outp += 24;
    }

    // x_model stage 1: hid = ReLU(W1 x^T + b1)  (this wave: hid rows 16w.., 64+16w..)
    f32x4 hid0 = b1a;
    hid0 = MFMA(aW1_00, xB0, hid0); hid0 = MFMA(aW1_01, xB1, hid0);
    f32x4 hid1 = b1b;
    hid1 = MFMA(aW1_10, xB0, hid1); hid1 = MFMA(aW1_11, xB1, hid1);
#pragma unroll
    for (int j = 0; j < 4; ++j) { hid0[j] = fmaxf(hid0[j], 0.f); hid1[j] = fmaxf(hid1[j], 0.f); }
    *(short4v*)(HIDb + sHidW0) = cvt4(hid0);
    *(short4v*)(HIDb + sHidW1) = cvt4(hid1);

    // ODE gates r,z — separate hi/lo accumulators (chain depth 2, 2-way ILP)
    f32x4 rph = {0.f, 0.f, 0.f, 0.f}, rpl = {0.f, 0.f, 0.f, 0.f};
    rph = MFMA(aR0, hB0h, rph); rph = MFMA(aR1, hB1h, rph);
    rpl = MFMA(aR0, hB0l, rpl); rpl = MFMA(aR1, hB1l, rpl);
    f32x4 zph = {0.f, 0.f, 0.f, 0.f}, zpl = {0.f, 0.f, 0.f, 0.f};
    zph = MFMA(aZ0, hB0h, zph); zph = MFMA(aZ1, hB1h, zph);
    zpl = MFMA(aZ0, hB0l, zpl); zpl = MFMA(aZ1, hB1l, zpl);
    f32x4 rr = sigm4(rph + rpl);
    f32x4 zz = sigm4(zph + zpl);
    {
      short4v phi, plo; split4(rr * hreg, phi, plo);
      *(short4v*)(RHhi + sW) = phi;
      *(short4v*)(RHlo + sW) = plo;
    }
    barrier_lds();

    // ================= P1 =================
    bf16x8 rhB0h = *(const bf16x8*)(RHhi + sR0);
    bf16x8 rhB1h = *(const bf16x8*)(RHhi + sR1);
    bf16x8 rhB0l = *(const bf16x8*)(RHlo + sR0);
    bf16x8 rhB1l = *(const bf16x8*)(RHlo + sR1);
    bf16x8 hdB0 = *(const bf16x8*)(HIDb + sHid0);
    bf16x8 hdB1 = *(const bf16x8*)(HIDb + sHid1);
    bf16x8 hdB2 = *(const bf16x8*)(HIDb + sHid2);
    bf16x8 hdB3 = *(const bf16x8*)(HIDb + sHid3);

    f32x4 uph = {0.f, 0.f, 0.f, 0.f}, upl = {0.f, 0.f, 0.f, 0.f};
    uph = MFMA(aU0, rhB0h, uph); uph = MFMA(aU1, rhB1h, uph);
    upl = MFMA(aU0, rhB0l, upl); upl = MFMA(aU1, rhB1l, upl);
    f32x4 uu = tanh4(uph + upl);
    f32x4 hp = hreg + (1.f - zz) * (uu - hreg);  // ODE Euler step (DT=1)
    {
      short4v phi, plo; split4(hp, phi, plo);
      *(short4v*)(H2hi + sW) = phi;
      *(short4v*)(H2lo + sW) = plo;
    }
    // x_model stage 2: HH_t = W2 hid^T + b2 (this wave: rows 16w..)
    f32x4 xg = b2w;
    xg = MFMA(aW2_0, hdB0, xg); xg = MFMA(aW2_1, hdB1, xg);
    xg = MFMA(aW2_2, hdB2, xg); xg = MFMA(aW2_3, hdB3, xg);
    *(short4v*)(XGb + sW) = cvt4(xg);
    barrier_lds();

    // ================= P2 =================
    bf16x8 xgB0 = *(const bf16x8*)(XGb + sR0);
    bf16x8 xgB1 = *(const bf16x8*)(XGb + sR1);
    bf16x8 h2B0h = *(const bf16x8*)(H2hi + sR0);
    bf16x8 h2B1h = *(const bf16x8*)(H2hi + sR1);
    bf16x8 h2B0l = *(const bf16x8*)(H2lo + sR0);
    bf16x8 h2B1l = *(const bf16x8*)(H2lo + sR1);

    f32x4 ir = bsr;
    ir = MFMA(aIR0, xgB0, ir); ir = MFMA(aIR1, xgB1, ir);
    f32x4 iz = bsz;
    iz = MFMA(aIZ0, xgB0, iz); iz = MFMA(aIZ1, xgB1, iz);
    f32x4 inn = bin_;
    inn = MFMA(aIN0, xgB0, inn); inn = MFMA(aIN1, xgB1, inn);
    f32x4 hrh = {0.f, 0.f, 0.f, 0.f}, hrl = {0.f, 0.f, 0.f, 0.f};
    hrh = MFMA(aHR0, h2B0h, hrh); hrh = MFMA(aHR1, h2B1h, hrh);
    hrl = MFMA(aHR0, h2B0l, hrl); hrl = MFMA(aHR1, h2B1l, hrl);
    f32x4 hzh = {0.f, 0.f, 0.f, 0.f}, hzl = {0.f, 0.f, 0.f, 0.f};
    hzh = MFMA(aHZ0, h2B0h, hzh); hzh = MFMA(aHZ1, h2B1h, hzh);
    hzl = MFMA(aHZ0, h2B0l, hzl); hzl = MFMA(aHZ1, h2B1l, hzl);
    f32x4 hnh = bhn, hnl = {0.f, 0.f, 0.f, 0.f};
    hnh = MFMA(aHN0, h2B0h, hnh); hnh = MFMA(aHN1, h2B1h, hnh);
    hnl = MFMA(aHN0, h2B0l, hnl); hnl = MFMA(aHN1, h2B1l, hnl);

    f32x4 r2 = sigm4(ir + hrh + hrl);
    f32x4 z2 = sigm4(iz + hzh + hzl);
    f32x4 nn = tanh4(inn + r2 * (hnh + hnl));
    hreg = (1.f - z2) * nn + z2 * hp;  // GRU update; h_new
    {
      short4v phi, plo; split4(hreg, phi, plo);
      *(short4v*)(Hhi + sW) = phi;
      *(short4v*)(Hlo + sW) = plo;
    }
    barrier_lds();
  }

  // epilogue: output for t = T-1
  if (w < 2) {
    bf16x8 hB0h = *(const bf16x8*)(Hhi + sR0);
    bf16x8 hB1h = *(const bf16x8*)(Hhi + sR1);
    bf16x8 hB0l = *(const bf16x8*)(Hlo + sR0);
    bf16x8 hB1l = *(const bf16x8*)(Hlo + sR1);
    f32x4 a5 = brw, a5l = {0.f, 0.f, 0.f, 0.f};
    a5 = MFMA(aWr0, hB0h, a5);  a5 = MFMA(aWr1, hB1h, a5);
    a5l = MFMA(aWr0, hB0l, a5l); a5l = MFMA(aWr1, hB1l, a5l);
    a5 += a5l;
    if (w == 0 || g < 2) { outp[0] = a5[0]; outp[1] = a5[1]; outp[2] = a5[2]; outp[3] = a5[3]; }
  }
}

extern "C" void kernel_launch(void* const* d_in, const int* in_sizes, int n_in,
                              void* d_out, int out_size, void* d_ws, size_t ws_size,
                              hipStream_t stream) {
  (void)in_sizes; (void)n_in; (void)d_ws; (void)ws_size; (void)out_size;
  const float* H   = (const float*)d_in[0];
  // d_in[1] = times (unused: delta_t == 1 -> exactly one Euler step per observation)
  const float* W1  = (const float*)d_in[2];
  const float* b1  = (const float*)d_in[3];
  const float* W2  = (const float*)d_in[4];
  const float* b2  = (const float*)d_in[5];
  const float* Whr = (const float*)d_in[6];
  const float* Whz = (const float*)d_in[7];
  const float* Whh = (const float*)d_in[8];
  const float* wih = (const float*)d_in[9];
  const float* whh = (const float*)d_in[10];
  const float* bih = (const float*)d_in[11];
  const float* bhh = (const float*)d_in[12];
  const float* Wr  = (const float*)d_in[13];
  const float* br  = (const float*)d_in[14];
  float* out = (float*)d_out;

  odegru<<<dim3(2048 / 16), dim3(256), 0, stream>>>(
      H, W1, b1, W2, b2, Whr, Whz, Whh, wih, whh, bih, bhh, Wr, br, out);
}

// Round 3
// 399.194 us; speedup vs baseline: 1.2075x; 1.1141x over previous
//
#include <hip/hip_runtime.h>
#include <hip/hip_bf16.h>

// RecoveryODENetwork: fused x_model + GRU-ODE scan + output head, single kernel.
// B=2048, T=256, I=64, XH=128, G=Hd=64, O=24.
// Transposed matmuls Dt = W * h^T with MFMA 16x16x32 bf16.
//   A-frag (weights, const): lane holds A[row=l&15][k=8*(l>>4)+e]
//   B-frag (activations):    lane holds B[k=8*(l>>4)+e][col=l&15]   (col = batch)
//   D:                       lane holds D[row=4*(l>>4)+j][col=l&15] (m89-verified)
// R3: role-split waves. Block = 512 threads = 8 waves on 16 batch cols.
//   Waves 0-3 (critical): the recurrence chain only: r,z -> r*h -> u -> h' ->
//     h-gates -> h_new. 24 MFMA/step (was 42).
//   Waves 4-7 (helper): x_model one step ahead (hid_{t+1}, xg_{t+1}), GI_t =
//     w_ih*xg_t + biases (f32, exact, via LDS), output head for t-1.
//   2 waves/SIMD: helper fills critical wave's latency bubbles.
// Recurrent operands (h, r*h, h') in LDS as bf16 hi+lo splits (exactness).
// Lite barriers (lgkmcnt only) keep x-prefetch global loads in flight.

#define T_STEPS 256

typedef short bf16x8 __attribute__((ext_vector_type(8)));
typedef short short4v __attribute__((ext_vector_type(4)));
typedef float f32x4 __attribute__((ext_vector_type(4)));

#define MFMA(a, b, c) __builtin_amdgcn_mfma_f32_16x16x32_bf16((a), (b), (c), 0, 0, 0)

// LDS-only barrier: orders ds ops across the block WITHOUT draining vmcnt.
__device__ __forceinline__ void barrier_lds() {
  asm volatile("s_waitcnt lgkmcnt(0)\n\ts_barrier" ::: "memory");
}

__device__ __forceinline__ short f2bf(float f) {
  __hip_bfloat16 b = __float2bfloat16(f);
  return __builtin_bit_cast(short, b);
}
__device__ __forceinline__ float bf2f(short s) {
  return __builtin_bit_cast(float, ((unsigned)(unsigned short)s) << 16);
}

__device__ __forceinline__ f32x4 sigm4(f32x4 x) {
  f32x4 r;
#pragma unroll
  for (int j = 0; j < 4; ++j) {
    float e = __builtin_amdgcn_exp2f(-1.442695041f * x[j]);
    r[j] = __builtin_amdgcn_rcpf(1.f + e);
  }
  return r;
}
__device__ __forceinline__ f32x4 tanh4(f32x4 x) {
  f32x4 r;
#pragma unroll
  for (int j = 0; j < 4; ++j) {
    float xx = fmaxf(fminf(x[j], 30.f), -30.f);
    float e = __builtin_amdgcn_exp2f(-2.885390082f * xx);  // e^{-2x}
    r[j] = (1.f - e) * __builtin_amdgcn_rcpf(1.f + e);
  }
  return r;
}
__device__ __forceinline__ short4v cvt4(f32x4 v) {
  short4v p;
#pragma unroll
  for (int j = 0; j < 4; ++j) p[j] = f2bf(v[j]);
  return p;
}
// hi = truncate (1 op), lo = RNE(residual). Combined error ~2^-17 rel.
__device__ __forceinline__ void split4(f32x4 v, short4v& hi, short4v& lo) {
#pragma unroll
  for (int j = 0; j < 4; ++j) {
    unsigned u = __builtin_bit_cast(unsigned, v[j]);
    hi[j] = (short)(u >> 16);
    lo[j] = f2bf(v[j] - __builtin_bit_cast(float, u & 0xFFFF0000u));
  }
}
__device__ __forceinline__ bf16x8 wfrag(const float* __restrict__ W, int stride, int row, int c0) {
  const float* p = W + (size_t)row * stride + c0;
  float4 a = *(const float4*)p;
  float4 b = *(const float4*)(p + 4);
  bf16x8 r;
  r[0] = f2bf(a.x); r[1] = f2bf(a.y); r[2] = f2bf(a.z); r[3] = f2bf(a.w);
  r[4] = f2bf(b.x); r[5] = f2bf(b.y); r[6] = f2bf(b.z); r[7] = f2bf(b.w);
  return r;
}

// XOR swizzle (G4): kills 16-way bank conflict of stride-128B/256B column reads
__device__ __forceinline__ int swz64(int row, int off) { return row * 128 + (off ^ ((row & 7) << 4)); }
__device__ __forceinline__ int swzH(int row, int off)  { return row * 256 + (off ^ ((row & 7) << 4)); }

__global__ __launch_bounds__(512, 1) void odegru(
    const float* __restrict__ H,
    const float* __restrict__ W1, const float* __restrict__ b1,
    const float* __restrict__ W2, const float* __restrict__ b2,
    const float* __restrict__ Wor, const float* __restrict__ Woz, const float* __restrict__ Woh,
    const float* __restrict__ wih, const float* __restrict__ whhg,
    const float* __restrict__ bih, const float* __restrict__ bhh,
    const float* __restrict__ Wr, const float* __restrict__ br,
    float* __restrict__ out) {
  const int tid = threadIdx.x;
  const int w = tid >> 6;          // wave 0..7
  const int l = tid & 63;
  const int col = l & 15;          // batch column within tile
  const int g = l >> 4;            // lane group
  const int b0 = blockIdx.x << 4;
  const bool helper = (w >= 4);
  const int hw = w - 4;            // helper wave index 0..3

  __shared__ __align__(16) char sm[30720];
  char* HIDb = sm;            // [16 cols][256B] bf16 hid (x_model stage1), swizzled
  char* XGb  = sm + 4096;     // [16 cols][128B] bf16 xg, swizzled
  char* Hhi  = sm + 6144;     // h state hi
  char* Hlo  = sm + 8192;     // h state lo
  char* RHhi = sm + 10240;    // r*h hi
  char* RHlo = sm + 12288;    // r*h lo
  char* H2hi = sm + 14336;    // h' hi
  char* H2lo = sm + 16384;    // h' lo
  char* GIb  = sm + 18432;    // [gate3][tile4][plane2][lane64] float2 = 12288B

  // zero h state (hi+lo): 4096B, 512 threads x 8B
  ((long long*)Hhi)[tid] = 0;

  // ---- common LDS offsets ----
  const int row4 = 16 * (helper ? hw : w) + 4 * g;  // D-row base of this wave's tile
  const int r16 = 16 * (helper ? hw : w) + col;     // A-frag row base
  const int sR0 = swz64(col, 16 * g);
  const int sR1 = swz64(col, 64 + 16 * g);
  const int sW  = swz64(col, row4 * 2);

  // =======================================================================
  // per-role setup
  // =======================================================================
  // critical-wave weight frags
  bf16x8 aR0, aR1, aZ0, aZ1, aU0, aU1, aHR0, aHR1, aHZ0, aHZ1, aHN0, aHN1;
  f32x4 bhn;
  // helper weight frags
  bf16x8 aW1_00, aW1_01, aW1_10, aW1_11, aW2_0, aW2_1, aW2_2, aW2_3;
  bf16x8 aIR0, aIR1, aIZ0, aIZ1, aIN0, aIN1, aWr0, aWr1;
  f32x4 bsr, bsz, bin_, b1a, b1b, b2w, brw;
  // helper x prefetch
  const float* xp = nullptr;
  float4 xa, xb, xc, xd;
  float* outp = nullptr;
  // helper LDS offsets
  int sHid0, sHid1, sHid2, sHid3, sHidW0, sHidW1, giW;
  // critical GI read base
  const int giR = w * 1024 + l * 8;

  if (!helper) {
    aR0 = wfrag(Wor, 64, r16, 8 * g);          aR1 = wfrag(Wor, 64, r16, 32 + 8 * g);
    aZ0 = wfrag(Woz, 64, r16, 8 * g);          aZ1 = wfrag(Woz, 64, r16, 32 + 8 * g);
    aU0 = wfrag(Woh, 64, r16, 8 * g);          aU1 = wfrag(Woh, 64, r16, 32 + 8 * g);
    aHR0 = wfrag(whhg, 64, r16, 8 * g);        aHR1 = wfrag(whhg, 64, r16, 32 + 8 * g);
    aHZ0 = wfrag(whhg, 64, 64 + r16, 8 * g);   aHZ1 = wfrag(whhg, 64, 64 + r16, 32 + 8 * g);
    aHN0 = wfrag(whhg, 64, 128 + r16, 8 * g);  aHN1 = wfrag(whhg, 64, 128 + r16, 32 + 8 * g);
#pragma unroll
    for (int j = 0; j < 4; ++j) bhn[j] = bhh[128 + row4 + j];
  } else {
    aW1_00 = wfrag(W1, 64, r16, 8 * g);        aW1_01 = wfrag(W1, 64, r16, 32 + 8 * g);
    aW1_10 = wfrag(W1, 64, 64 + r16, 8 * g);   aW1_11 = wfrag(W1, 64, 64 + r16, 32 + 8 * g);
    aW2_0 = wfrag(W2, 128, r16, 8 * g);        aW2_1 = wfrag(W2, 128, r16, 32 + 8 * g);
    aW2_2 = wfrag(W2, 128, r16, 64 + 8 * g);   aW2_3 = wfrag(W2, 128, r16, 96 + 8 * g);
    aIR0 = wfrag(wih, 64, r16, 8 * g);         aIR1 = wfrag(wih, 64, r16, 32 + 8 * g);
    aIZ0 = wfrag(wih, 64, 64 + r16, 8 * g);    aIZ1 = wfrag(wih, 64, 64 + r16, 32 + 8 * g);
    aIN0 = wfrag(wih, 64, 128 + r16, 8 * g);   aIN1 = wfrag(wih, 64, 128 + r16, 32 + 8 * g);
    const int wr_row = r16 > 23 ? 23 : r16;    // Wr has 24 rows; clamp (unused rows)
    aWr0 = wfrag(Wr, 64, wr_row, 8 * g);       aWr1 = wfrag(Wr, 64, wr_row, 32 + 8 * g);
#pragma unroll
    for (int j = 0; j < 4; ++j) {
      bsr[j] = bih[row4 + j] + bhh[row4 + j];
      bsz[j] = bih[64 + row4 + j] + bhh[64 + row4 + j];
      bin_[j] = bih[128 + row4 + j];
      b1a[j] = b1[row4 + j];
      b1b[j] = b1[64 + row4 + j];
      b2w[j] = b2[row4 + j];
      int o = row4 + j;
      brw[j] = br[o > 23 ? 23 : o];
    }
    sHid0 = swzH(col, 16 * g);
    sHid1 = swzH(col, 64 + 16 * g);
    sHid2 = swzH(col, 128 + 16 * g);
    sHid3 = swzH(col, 192 + 16 * g);
    sHidW0 = swzH(col, row4 * 2);
    sHidW1 = swzH(col, (64 + row4) * 2);
    giW = hw * 1024 + l * 8;
    xp = H + ((size_t)(b0 + col) * T_STEPS) * 64 + 8 * g;
    xa = *(const float4*)(xp);      xb = *(const float4*)(xp + 4);
    xc = *(const float4*)(xp + 32); xd = *(const float4*)(xp + 36);
    outp = out + ((size_t)(b0 + col) * T_STEPS) * 24 + row4;
  }

  f32x4 hreg = {0.f, 0.f, 0.f, 0.f};  // critical: h^T[row4+j][col] in fp32

  // =======================================================================
  // prologue: helpers compute hid_0, xg_0 so GI_0 is ready in loop iter 0
  // =======================================================================
  if (helper) {
    bf16x8 xB0, xB1;
    xB0[0] = f2bf(xa.x); xB0[1] = f2bf(xa.y); xB0[2] = f2bf(xa.z); xB0[3] = f2bf(xa.w);
    xB0[4] = f2bf(xb.x); xB0[5] = f2bf(xb.y); xB0[6] = f2bf(xb.z); xB0[7] = f2bf(xb.w);
    xB1[0] = f2bf(xc.x); xB1[1] = f2bf(xc.y); xB1[2] = f2bf(xc.z); xB1[3] = f2bf(xc.w);
    xB1[4] = f2bf(xd.x); xB1[5] = f2bf(xd.y); xB1[6] = f2bf(xd.z); xB1[7] = f2bf(xd.w);
    f32x4 hid0 = b1a;
    hid0 = MFMA(aW1_00, xB0, hid0); hid0 = MFMA(aW1_01, xB1, hid0);
    f32x4 hid1 = b1b;
    hid1 = MFMA(aW1_10, xB0, hid1); hid1 = MFMA(aW1_11, xB1, hid1);
#pragma unroll
    for (int j = 0; j < 4; ++j) { hid0[j] = fmaxf(hid0[j], 0.f); hid1[j] = fmaxf(hid1[j], 0.f); }
    *(short4v*)(HIDb + sHidW0) = cvt4(hid0);
    *(short4v*)(HIDb + sHidW1) = cvt4(hid1);
  }
  barrier_lds();
  if (helper) {
    bf16x8 hdB0 = *(const bf16x8*)(HIDb + sHid0);
    bf16x8 hdB1 = *(const bf16x8*)(HIDb + sHid1);
    bf16x8 hdB2 = *(const bf16x8*)(HIDb + sHid2);
    bf16x8 hdB3 = *(const bf16x8*)(HIDb + sHid3);
    f32x4 xg = b2w;
    xg = MFMA(aW2_0, hdB0, xg); xg = MFMA(aW2_1, hdB1, xg);
    xg = MFMA(aW2_2, hdB2, xg); xg = MFMA(aW2_3, hdB3, xg);
    *(short4v*)(XGb + sW) = cvt4(xg);
    // advance prefetch: regs <- x_1
    xp += 64;
    xa = *(const float4*)(xp);      xb = *(const float4*)(xp + 4);
    xc = *(const float4*)(xp + 32); xd = *(const float4*)(xp + 36);
  }
  barrier_lds();

  // =======================================================================
  // main scan
  // =======================================================================
  for (int t = 0; t < T_STEPS; ++t) {
    // ================= Phase A (helpers) || P0 (critical) =================
    if (helper) {
      // GI_t = w_ih * xg_t + (biases); XGb holds xg_t
      bf16x8 xgB0 = *(const bf16x8*)(XGb + sR0);
      bf16x8 xgB1 = *(const bf16x8*)(XGb + sR1);
      // output head for t-1 (Hhi/Hlo hold h_{t-1})
      if (hw < 2 && t > 0) {
        bf16x8 hB0h = *(const bf16x8*)(Hhi + sR0);
        bf16x8 hB1h = *(const bf16x8*)(Hhi + sR1);
        bf16x8 hB0l = *(const bf16x8*)(Hlo + sR0);
        bf16x8 hB1l = *(const bf16x8*)(Hlo + sR1);
        f32x4 a5 = brw, a5l = {0.f, 0.f, 0.f, 0.f};
        a5 = MFMA(aWr0, hB0h, a5);   a5 = MFMA(aWr1, hB1h, a5);
        a5l = MFMA(aWr0, hB0l, a5l); a5l = MFMA(aWr1, hB1l, a5l);
        a5 += a5l;
        if (hw == 0 || g < 2) { outp[0] = a5[0]; outp[1] = a5[1]; outp[2] = a5[2]; outp[3] = a5[3]; }
        outp += 24;
      }
      f32x4 gir = bsr;
      gir = MFMA(aIR0, xgB0, gir); gir = MFMA(aIR1, xgB1, gir);
      f32x4 giz = bsz;
      giz = MFMA(aIZ0, xgB0, giz); giz = MFMA(aIZ1, xgB1, giz);
      f32x4 gin = bin_;
      gin = MFMA(aIN0, xgB0, gin); gin = MFMA(aIN1, xgB1, gin);
      *(float2*)(GIb + 0 * 4096 + giW)       = make_float2(gir[0], gir[1]);
      *(float2*)(GIb + 0 * 4096 + giW + 512) = make_float2(gir[2], gir[3]);
      *(float2*)(GIb + 1 * 4096 + giW)       = make_float2(giz[0], giz[1]);
      *(float2*)(GIb + 1 * 4096 + giW + 512) = make_float2(giz[2], giz[3]);
      *(float2*)(GIb + 2 * 4096 + giW)       = make_float2(gin[0], gin[1]);
      *(float2*)(GIb + 2 * 4096 + giW + 512) = make_float2(gin[2], gin[3]);
      // hid_{t+1} from x_{t+1} (in regs)
      if (t + 1 < T_STEPS) {
        bf16x8 xB0, xB1;
        xB0[0] = f2bf(xa.x); xB0[1] = f2bf(xa.y); xB0[2] = f2bf(xa.z); xB0[3] = f2bf(xa.w);
        xB0[4] = f2bf(xb.x); xB0[5] = f2bf(xb.y); xB0[6] = f2bf(xb.z); xB0[7] = f2bf(xb.w);
        xB1[0] = f2bf(xc.x); xB1[1] = f2bf(xc.y); xB1[2] = f2bf(xc.z); xB1[3] = f2bf(xc.w);
        xB1[4] = f2bf(xd.x); xB1[5] = f2bf(xd.y); xB1[6] = f2bf(xd.z); xB1[7] = f2bf(xd.w);
        if (t + 2 < T_STEPS) {  // prefetch x_{t+2}; stays in flight across lite barriers
          xp += 64;
          xa = *(const float4*)(xp);      xb = *(const float4*)(xp + 4);
          xc = *(const float4*)(xp + 32); xd = *(const float4*)(xp + 36);
        }
        f32x4 hid0 = b1a;
        hid0 = MFMA(aW1_00, xB0, hid0); hid0 = MFMA(aW1_01, xB1, hid0);
        f32x4 hid1 = b1b;
        hid1 = MFMA(aW1_10, xB0, hid1); hid1 = MFMA(aW1_11, xB1, hid1);
#pragma unroll
        for (int j = 0; j < 4; ++j) { hid0[j] = fmaxf(hid0[j], 0.f); hid1[j] = fmaxf(hid1[j], 0.f); }
        *(short4v*)(HIDb + sHidW0) = cvt4(hid0);
        *(short4v*)(HIDb + sHidW1) = cvt4(hid1);
      }
    } else {
      // P0: r,z = sigma(W{r,z} h); write r*h (hi/lo). z-sigmoid deferred past write.
      bf16x8 hB0h = *(const bf16x8*)(Hhi + sR0);
      bf16x8 hB1h = *(const bf16x8*)(Hhi + sR1);
      bf16x8 hB0l = *(const bf16x8*)(Hlo + sR0);
      bf16x8 hB1l = *(const bf16x8*)(Hlo + sR1);
      f32x4 rph = {0.f, 0.f, 0.f, 0.f}, rpl = {0.f, 0.f, 0.f, 0.f};
      rph = MFMA(aR0, hB0h, rph); rph = MFMA(aR1, hB1h, rph);
      rpl = MFMA(aR0, hB0l, rpl); rpl = MFMA(aR1, hB1l, rpl);
      f32x4 zph = {0.f, 0.f, 0.f, 0.f}, zpl = {0.f, 0.f, 0.f, 0.f};
      zph = MFMA(aZ0, hB0h, zph); zph = MFMA(aZ1, hB1h, zph);
      zpl = MFMA(aZ0, hB0l, zpl); zpl = MFMA(aZ1, hB1l, zpl);
      f32x4 rr = sigm4(rph + rpl);
      {
        short4v phi, plo; split4(rr * hreg, phi, plo);
        *(short4v*)(RHhi + sW) = phi;
        *(short4v*)(RHlo + sW) = plo;
      }
      f32x4 zz = sigm4(zph + zpl);  // after RH write: overlaps barrier wait
      hreg[0] = hreg[0]; (void)zz;  // keep zz live into P1 (below)
      // stash zz in hreg-adjacent? No: keep in scope — fallthrough via variables
      // (zz, hreg used in P1 block below; C++ scope spans phases)
      barrier_lds();
      // ================= P1 (critical) =================
      bf16x8 rhB0h = *(const bf16x8*)(RHhi + sR0);
      bf16x8 rhB1h = *(const bf16x8*)(RHhi + sR1);
      bf16x8 rhB0l = *(const bf16x8*)(RHlo + sR0);
      bf16x8 rhB1l = *(const bf16x8*)(RHlo + sR1);
      f32x4 uph = {0.f, 0.f, 0.f, 0.f}, upl = {0.f, 0.f, 0.f, 0.f};
      uph = MFMA(aU0, rhB0h, uph); uph = MFMA(aU1, rhB1h, uph);
      upl = MFMA(aU0, rhB0l, upl); upl = MFMA(aU1, rhB1l, upl);
      f32x4 uu = tanh4(uph + upl);
      f32x4 hp = hreg + (1.f - zz) * (uu - hreg);  // ODE Euler step (DT=1)
      {
        short4v phi, plo; split4(hp, phi, plo);
        *(short4v*)(H2hi + sW) = phi;
        *(short4v*)(H2lo + sW) = plo;
      }
      barrier_lds();
      // ================= P2 (critical) =================
      bf16x8 h2B0h = *(const bf16x8*)(H2hi + sR0);
      bf16x8 h2B1h = *(const bf16x8*)(H2hi + sR1);
      bf16x8 h2B0l = *(const bf16x8*)(H2lo + sR0);
      bf16x8 h2B1l = *(const bf16x8*)(H2lo + sR1);
      float2 g01, g23;
      g01 = *(const float2*)(GIb + 0 * 4096 + giR);
      g23 = *(const float2*)(GIb + 0 * 4096 + giR + 512);
      f32x4 gir = {g01.x, g01.y, g23.x, g23.y};
      g01 = *(const float2*)(GIb + 1 * 4096 + giR);
      g23 = *(const float2*)(GIb + 1 * 4096 + giR + 512);
      f32x4 giz = {g01.x, g01.y, g23.x, g23.y};
      g01 = *(const float2*)(GIb + 2 * 4096 + giR);
      g23 = *(const float2*)(GIb + 2 * 4096 + giR + 512);
      f32x4 gin = {g01.x, g01.y, g23.x, g23.y};

      f32x4 hrh = {0.f, 0.f, 0.f, 0.f}, hrl = {0.f, 0.f, 0.f, 0.f};
      hrh = MFMA(aHR0, h2B0h, hrh); hrh = MFMA(aHR1, h2B1h, hrh);
      hrl = MFMA(aHR0, h2B0l, hrl); hrl = MFMA(aHR1, h2B1l, hrl);
      f32x4 hzh = {0.f, 0.f, 0.f, 0.f}, hzl = {0.f, 0.f, 0.f, 0.f};
      hzh = MFMA(aHZ0, h2B0h, hzh); hzh = MFMA(aHZ1, h2B1h, hzh);
      hzl = MFMA(aHZ0, h2B0l, hzl); hzl = MFMA(aHZ1, h2B1l, hzl);
      f32x4 hnh = bhn, hnl = {0.f, 0.f, 0.f, 0.f};
      hnh = MFMA(aHN0, h2B0h, hnh); hnh = MFMA(aHN1, h2B1h, hnh);
      hnl = MFMA(aHN0, h2B0l, hnl); hnl = MFMA(aHN1, h2B1l, hnl);

      f32x4 r2 = sigm4(gir + hrh + hrl);
      f32x4 z2 = sigm4(giz + hzh + hzl);
      f32x4 nn = tanh4(gin + r2 * (hnh + hnl));
      hreg = (1.f - z2) * nn + z2 * hp;  // h_new
      {
        short4v phi, plo; split4(hreg, phi, plo);
        *(short4v*)(Hhi + sW) = phi;
        *(short4v*)(Hlo + sW) = plo;
      }
      barrier_lds();
      continue;  // critical wave: barriers consumed inside this branch
    }
    // helper wave: match the critical wave's 3 barriers per step
    barrier_lds();
    // Phase B (helpers): xg_{t+1} = W2 * hid_{t+1} + b2
    if (t + 1 < T_STEPS) {
      bf16x8 hdB0 = *(const bf16x8*)(HIDb + sHid0);
      bf16x8 hdB1 = *(const bf16x8*)(HIDb + sHid1);
      bf16x8 hdB2 = *(const bf16x8*)(HIDb + sHid2);
      bf16x8 hdB3 = *(const bf16x8*)(HIDb + sHid3);
      f32x4 xg = b2w;
      xg = MFMA(aW2_0, hdB0, xg); xg = MFMA(aW2_1, hdB1, xg);
      xg = MFMA(aW2_2, hdB2, xg); xg = MFMA(aW2_3, hdB3, xg);
      *(short4v*)(XGb + sW) = cvt4(xg);
    }
    barrier_lds();
    // (P2 window: helpers idle)
    barrier_lds();
  }

  // epilogue: output head for t = T-1 (Hhi/Hlo hold h_{T-1})
  if (helper && hw < 2) {
    bf16x8 hB0h = *(const bf16x8*)(Hhi + sR0);
    bf16x8 hB1h = *(const bf16x8*)(Hhi + sR1);
    bf16x8 hB0l = *(const bf16x8*)(Hlo + sR0);
    bf16x8 hB1l = *(const bf16x8*)(Hlo + sR1);
    f32x4 a5 = brw, a5l = {0.f, 0.f, 0.f, 0.f};
    a5 = MFMA(aWr0, hB0h, a5);   a5 = MFMA(aWr1, hB1h, a5);
    a5l = MFMA(aWr0, hB0l, a5l); a5l = MFMA(aWr1, hB1l, a5l);
    a5 += a5l;
    if (hw == 0 || g < 2) { outp[0] = a5[0]; outp[1] = a5[1]; outp[2] = a5[2]; outp[3] = a5[3]; }
  }
}

extern "C" void kernel_launch(void* const* d_in, const int* in_sizes, int n_in,
                              void* d_out, int out_size, void* d_ws, size_t ws_size,
                              hipStream_t stream) {
  (void)in_sizes; (void)n_in; (void)d_ws; (void)ws_size; (void)out_size;
  const float* H   = (const float*)d_in[0];
  // d_in[1] = times (unused: delta_t == 1 -> exactly one Euler step per observation)
  const float* W1  = (const float*)d_in[2];
  const float* b1  = (const float*)d_in[3];
  const float* W2  = (const float*)d_in[4];
  const float* b2  = (const float*)d_in[5];
  const float* Whr = (const float*)d_in[6];
  const float* Whz = (const float*)d_in[7];
  const float* Whh = (const float*)d_in[8];
  const float* wih = (const float*)d_in[9];
  const float* whh = (const float*)d_in[10];
  const float* bih = (const float*)d_in[11];
  const float* bhh = (const float*)d_in[12];
  const float* Wr  = (const float*)d_in[13];
  const float* br  = (const float*)d_in[14];
  float* out = (float*)d_out;

  odegru<<<dim3(2048 / 16), dim3(512), 0, stream>>>(
      H, W1, b1, W2, b2, Whr, Whz, Whh, wih, whh, bih, bhh, Wr, br, out);
}

// Round 4
// 387.785 us; speedup vs baseline: 1.2431x; 1.0294x over previous
//
#include <hip/hip_runtime.h>
#include <hip/hip_bf16.h>

// RecoveryODENetwork: fused x_model + GRU-ODE scan + output head, single kernel.
// B=2048, T=256, I=64, XH=128, G=Hd=64, O=24.
// Transposed matmuls Dt = W * h^T with MFMA 16x16x32 bf16.
//   A-frag (weights, const): lane holds A[row=l&15][k=8*(l>>4)+e]
//   B-frag (activations):    lane holds B[k=8*(l>>4)+e][col=l&15]   (col = batch)
//   D:                       lane holds D[row=4*(l>>4)+j][col=l&15] (m89-verified)
// R3: role-split waves. Block = 512 threads = 8 waves on 16 batch cols.
//   Waves 0-3 (critical): recurrence chain: r,z -> r*h -> u -> h' -> gates -> h_new.
//   Waves 4-7 (helper): x_model pipeline + GI + output head.
// R4: window-balanced helper schedule (max MFMA per window 14 -> 10):
//   A: helper GI_t (+head t-1, hw<2)   | crit P0 (r,z: 8 MFMA)
//   B: helper hid_{t+1}                | crit P1 (u: 4 MFMA)      [crit prio 1]
//   C: helper xg_{t+1}                 | crit P2 (gates: 12 MFMA) [crit prio 1]
//   + GI handoff as one float4/gate/lane (identity lane mapping helper->crit).
// Recurrent operands (h, r*h, h') in LDS as bf16 hi+lo splits (exactness).
// Lite barriers (lgkmcnt only) keep x-prefetch global loads in flight.

#define T_STEPS 256

typedef short bf16x8 __attribute__((ext_vector_type(8)));
typedef short short4v __attribute__((ext_vector_type(4)));
typedef float f32x4 __attribute__((ext_vector_type(4)));

#define MFMA(a, b, c) __builtin_amdgcn_mfma_f32_16x16x32_bf16((a), (b), (c), 0, 0, 0)

// LDS-only barrier: orders ds ops across the block WITHOUT draining vmcnt.
__device__ __forceinline__ void barrier_lds() {
  asm volatile("s_waitcnt lgkmcnt(0)\n\ts_barrier" ::: "memory");
}

__device__ __forceinline__ short f2bf(float f) {
  __hip_bfloat16 b = __float2bfloat16(f);
  return __builtin_bit_cast(short, b);
}
__device__ __forceinline__ float bf2f(short s) {
  return __builtin_bit_cast(float, ((unsigned)(unsigned short)s) << 16);
}

__device__ __forceinline__ f32x4 sigm4(f32x4 x) {
  f32x4 r;
#pragma unroll
  for (int j = 0; j < 4; ++j) {
    float e = __builtin_amdgcn_exp2f(-1.442695041f * x[j]);
    r[j] = __builtin_amdgcn_rcpf(1.f + e);
  }
  return r;
}
__device__ __forceinline__ f32x4 tanh4(f32x4 x) {
  f32x4 r;
#pragma unroll
  for (int j = 0; j < 4; ++j) {
    float xx = fmaxf(fminf(x[j], 30.f), -30.f);
    float e = __builtin_amdgcn_exp2f(-2.885390082f * xx);  // e^{-2x}
    r[j] = (1.f - e) * __builtin_amdgcn_rcpf(1.f + e);
  }
  return r;
}
__device__ __forceinline__ short4v cvt4(f32x4 v) {
  short4v p;
#pragma unroll
  for (int j = 0; j < 4; ++j) p[j] = f2bf(v[j]);
  return p;
}
// hi = truncate (1 op), lo = RNE(residual). Combined error ~2^-17 rel.
__device__ __forceinline__ void split4(f32x4 v, short4v& hi, short4v& lo) {
#pragma unroll
  for (int j = 0; j < 4; ++j) {
    unsigned u = __builtin_bit_cast(unsigned, v[j]);
    hi[j] = (short)(u >> 16);
    lo[j] = f2bf(v[j] - __builtin_bit_cast(float, u & 0xFFFF0000u));
  }
}
__device__ __forceinline__ bf16x8 wfrag(const float* __restrict__ W, int stride, int row, int c0) {
  const float* p = W + (size_t)row * stride + c0;
  float4 a = *(const float4*)p;
  float4 b = *(const float4*)(p + 4);
  bf16x8 r;
  r[0] = f2bf(a.x); r[1] = f2bf(a.y); r[2] = f2bf(a.z); r[3] = f2bf(a.w);
  r[4] = f2bf(b.x); r[5] = f2bf(b.y); r[6] = f2bf(b.z); r[7] = f2bf(b.w);
  return r;
}

// XOR swizzle (G4): kills 16-way bank conflict of stride-128B/256B column reads
__device__ __forceinline__ int swz64(int row, int off) { return row * 128 + (off ^ ((row & 7) << 4)); }
__device__ __forceinline__ int swzH(int row, int off)  { return row * 256 + (off ^ ((row & 7) << 4)); }

__global__ __launch_bounds__(512, 1) void odegru(
    const float* __restrict__ H,
    const float* __restrict__ W1, const float* __restrict__ b1,
    const float* __restrict__ W2, const float* __restrict__ b2,
    const float* __restrict__ Wor, const float* __restrict__ Woz, const float* __restrict__ Woh,
    const float* __restrict__ wih, const float* __restrict__ whhg,
    const float* __restrict__ bih, const float* __restrict__ bhh,
    const float* __restrict__ Wr, const float* __restrict__ br,
    float* __restrict__ out) {
  const int tid = threadIdx.x;
  const int w = tid >> 6;          // wave 0..7
  const int l = tid & 63;
  const int col = l & 15;          // batch column within tile
  const int g = l >> 4;            // lane group
  const int b0 = blockIdx.x << 4;
  const bool helper = (w >= 4);
  const int hw = w - 4;            // helper wave index 0..3

  __shared__ __align__(16) char sm[30720];
  char* HIDb = sm;            // [16 cols][256B] bf16 hid (x_model stage1), swizzled
  char* XGb  = sm + 4096;     // [16 cols][128B] bf16 xg, swizzled
  char* Hhi  = sm + 6144;     // h state hi
  char* Hlo  = sm + 8192;     // h state lo
  char* RHhi = sm + 10240;    // r*h hi
  char* RHlo = sm + 12288;    // r*h lo
  char* H2hi = sm + 14336;    // h' hi
  char* H2lo = sm + 16384;    // h' lo
  char* GIb  = sm + 18432;    // [gate3][wave4][lane64] float4 = 12288B

  // zero h state (hi+lo): 4096B, 512 threads x 8B
  ((long long*)Hhi)[tid] = 0;

  // ---- common LDS offsets ----
  const int row4 = 16 * (helper ? hw : w) + 4 * g;  // D-row base of this wave's tile
  const int r16 = 16 * (helper ? hw : w) + col;     // A-frag row base
  const int sR0 = swz64(col, 16 * g);
  const int sR1 = swz64(col, 64 + 16 * g);
  const int sW  = swz64(col, row4 * 2);

  // =======================================================================
  // per-role setup
  // =======================================================================
  // critical-wave weight frags
  bf16x8 aR0, aR1, aZ0, aZ1, aU0, aU1, aHR0, aHR1, aHZ0, aHZ1, aHN0, aHN1;
  f32x4 bhn;
  // helper weight frags
  bf16x8 aW1_00, aW1_01, aW1_10, aW1_11, aW2_0, aW2_1, aW2_2, aW2_3;
  bf16x8 aIR0, aIR1, aIZ0, aIZ1, aIN0, aIN1, aWr0, aWr1;
  f32x4 bsr, bsz, bin_, b1a, b1b, b2w, brw;
  // helper x prefetch
  const float* xp = nullptr;
  float4 xa, xb, xc, xd;
  float* outp = nullptr;
  // helper LDS offsets
  int sHid0, sHid1, sHid2, sHid3, sHidW0, sHidW1, giW;
  // critical GI read base: identity mapping to helper hw==w, same lane
  const int giR = (w * 64 + l) * 16;

  if (!helper) {
    aR0 = wfrag(Wor, 64, r16, 8 * g);          aR1 = wfrag(Wor, 64, r16, 32 + 8 * g);
    aZ0 = wfrag(Woz, 64, r16, 8 * g);          aZ1 = wfrag(Woz, 64, r16, 32 + 8 * g);
    aU0 = wfrag(Woh, 64, r16, 8 * g);          aU1 = wfrag(Woh, 64, r16, 32 + 8 * g);
    aHR0 = wfrag(whhg, 64, r16, 8 * g);        aHR1 = wfrag(whhg, 64, r16, 32 + 8 * g);
    aHZ0 = wfrag(whhg, 64, 64 + r16, 8 * g);   aHZ1 = wfrag(whhg, 64, 64 + r16, 32 + 8 * g);
    aHN0 = wfrag(whhg, 64, 128 + r16, 8 * g);  aHN1 = wfrag(whhg, 64, 128 + r16, 32 + 8 * g);
#pragma unroll
    for (int j = 0; j < 4; ++j) bhn[j] = bhh[128 + row4 + j];
  } else {
    aW1_00 = wfrag(W1, 64, r16, 8 * g);        aW1_01 = wfrag(W1, 64, r16, 32 + 8 * g);
    aW1_10 = wfrag(W1, 64, 64 + r16, 8 * g);   aW1_11 = wfrag(W1, 64, 64 + r16, 32 + 8 * g);
    aW2_0 = wfrag(W2, 128, r16, 8 * g);        aW2_1 = wfrag(W2, 128, r16, 32 + 8 * g);
    aW2_2 = wfrag(W2, 128, r16, 64 + 8 * g);   aW2_3 = wfrag(W2, 128, r16, 96 + 8 * g);
    aIR0 = wfrag(wih, 64, r16, 8 * g);         aIR1 = wfrag(wih, 64, r16, 32 + 8 * g);
    aIZ0 = wfrag(wih, 64, 64 + r16, 8 * g);    aIZ1 = wfrag(wih, 64, 64 + r16, 32 + 8 * g);
    aIN0 = wfrag(wih, 64, 128 + r16, 8 * g);   aIN1 = wfrag(wih, 64, 128 + r16, 32 + 8 * g);
    const int wr_row = r16 > 23 ? 23 : r16;    // Wr has 24 rows; clamp (unused rows)
    aWr0 = wfrag(Wr, 64, wr_row, 8 * g);       aWr1 = wfrag(Wr, 64, wr_row, 32 + 8 * g);
#pragma unroll
    for (int j = 0; j < 4; ++j) {
      bsr[j] = bih[row4 + j] + bhh[row4 + j];
      bsz[j] = bih[64 + row4 + j] + bhh[64 + row4 + j];
      bin_[j] = bih[128 + row4 + j];
      b1a[j] = b1[row4 + j];
      b1b[j] = b1[64 + row4 + j];
      b2w[j] = b2[row4 + j];
      int o = row4 + j;
      brw[j] = br[o > 23 ? 23 : o];
    }
    sHid0 = swzH(col, 16 * g);
    sHid1 = swzH(col, 64 + 16 * g);
    sHid2 = swzH(col, 128 + 16 * g);
    sHid3 = swzH(col, 192 + 16 * g);
    sHidW0 = swzH(col, row4 * 2);
    sHidW1 = swzH(col, (64 + row4) * 2);
    giW = (hw * 64 + l) * 16;
    xp = H + ((size_t)(b0 + col) * T_STEPS) * 64 + 8 * g;
    xa = *(const float4*)(xp);      xb = *(const float4*)(xp + 4);
    xc = *(const float4*)(xp + 32); xd = *(const float4*)(xp + 36);
    outp = out + ((size_t)(b0 + col) * T_STEPS) * 24 + row4;
  }

  f32x4 hreg = {0.f, 0.f, 0.f, 0.f};  // critical: h^T[row4+j][col] in fp32

  // =======================================================================
  // prologue: helpers compute hid_0, xg_0 so GI_0 is ready in loop iter 0
  // =======================================================================
  if (helper) {
    bf16x8 xB0, xB1;
    xB0[0] = f2bf(xa.x); xB0[1] = f2bf(xa.y); xB0[2] = f2bf(xa.z); xB0[3] = f2bf(xa.w);
    xB0[4] = f2bf(xb.x); xB0[5] = f2bf(xb.y); xB0[6] = f2bf(xb.z); xB0[7] = f2bf(xb.w);
    xB1[0] = f2bf(xc.x); xB1[1] = f2bf(xc.y); xB1[2] = f2bf(xc.z); xB1[3] = f2bf(xc.w);
    xB1[4] = f2bf(xd.x); xB1[5] = f2bf(xd.y); xB1[6] = f2bf(xd.z); xB1[7] = f2bf(xd.w);
    f32x4 hid0 = b1a;
    hid0 = MFMA(aW1_00, xB0, hid0); hid0 = MFMA(aW1_01, xB1, hid0);
    f32x4 hid1 = b1b;
    hid1 = MFMA(aW1_10, xB0, hid1); hid1 = MFMA(aW1_11, xB1, hid1);
#pragma unroll
    for (int j = 0; j < 4; ++j) { hid0[j] = fmaxf(hid0[j], 0.f); hid1[j] = fmaxf(hid1[j], 0.f); }
    *(short4v*)(HIDb + sHidW0) = cvt4(hid0);
    *(short4v*)(HIDb + sHidW1) = cvt4(hid1);
  }
  barrier_lds();
  if (helper) {
    bf16x8 hdB0 = *(const bf16x8*)(HIDb + sHid0);
    bf16x8 hdB1 = *(const bf16x8*)(HIDb + sHid1);
    bf16x8 hdB2 = *(const bf16x8*)(HIDb + sHid2);
    bf16x8 hdB3 = *(const bf16x8*)(HIDb + sHid3);
    f32x4 xg = b2w;
    xg = MFMA(aW2_0, hdB0, xg); xg = MFMA(aW2_1, hdB1, xg);
    xg = MFMA(aW2_2, hdB2, xg); xg = MFMA(aW2_3, hdB3, xg);
    *(short4v*)(XGb + sW) = cvt4(xg);
    // advance prefetch: regs <- x_1 (consumed in window B of iter 0)
    xp += 64;
    xa = *(const float4*)(xp);      xb = *(const float4*)(xp + 4);
    xc = *(const float4*)(xp + 32); xd = *(const float4*)(xp + 36);
  }
  barrier_lds();

  // =======================================================================
  // main scan
  // =======================================================================
  for (int t = 0; t < T_STEPS; ++t) {
    if (helper) {
      // ============== window A: GI_t (+ head t-1) ==============
      bf16x8 xgB0 = *(const bf16x8*)(XGb + sR0);
      bf16x8 xgB1 = *(const bf16x8*)(XGb + sR1);
      if (hw < 2 && t > 0) {  // output head for t-1 (Hhi/Hlo hold h_{t-1})
        bf16x8 hB0h = *(const bf16x8*)(Hhi + sR0);
        bf16x8 hB1h = *(const bf16x8*)(Hhi + sR1);
        bf16x8 hB0l = *(const bf16x8*)(Hlo + sR0);
        bf16x8 hB1l = *(const bf16x8*)(Hlo + sR1);
        f32x4 a5 = brw, a5l = {0.f, 0.f, 0.f, 0.f};
        a5 = MFMA(aWr0, hB0h, a5);   a5 = MFMA(aWr1, hB1h, a5);
        a5l = MFMA(aWr0, hB0l, a5l); a5l = MFMA(aWr1, hB1l, a5l);
        a5 += a5l;
        if (hw == 0 || g < 2) { outp[0] = a5[0]; outp[1] = a5[1]; outp[2] = a5[2]; outp[3] = a5[3]; }
        outp += 24;
      }
      f32x4 gir = bsr;
      gir = MFMA(aIR0, xgB0, gir); gir = MFMA(aIR1, xgB1, gir);
      f32x4 giz = bsz;
      giz = MFMA(aIZ0, xgB0, giz); giz = MFMA(aIZ1, xgB1, giz);
      f32x4 gin = bin_;
      gin = MFMA(aIN0, xgB0, gin); gin = MFMA(aIN1, xgB1, gin);
      *(f32x4*)(GIb + 0 * 4096 + giW) = gir;
      *(f32x4*)(GIb + 1 * 4096 + giW) = giz;
      *(f32x4*)(GIb + 2 * 4096 + giW) = gin;
      barrier_lds();
      // ============== window B: hid_{t+1} ==============
      if (t + 1 < T_STEPS) {
        bf16x8 xB0, xB1;
        xB0[0] = f2bf(xa.x); xB0[1] = f2bf(xa.y); xB0[2] = f2bf(xa.z); xB0[3] = f2bf(xa.w);
        xB0[4] = f2bf(xb.x); xB0[5] = f2bf(xb.y); xB0[6] = f2bf(xb.z); xB0[7] = f2bf(xb.w);
        xB1[0] = f2bf(xc.x); xB1[1] = f2bf(xc.y); xB1[2] = f2bf(xc.z); xB1[3] = f2bf(xc.w);
        xB1[4] = f2bf(xd.x); xB1[5] = f2bf(xd.y); xB1[6] = f2bf(xd.z); xB1[7] = f2bf(xd.w);
        if (t + 2 < T_STEPS) {  // prefetch x_{t+2}; stays in flight across lite barriers
          xp += 64;
          xa = *(const float4*)(xp);      xb = *(const float4*)(xp + 4);
          xc = *(const float4*)(xp + 32); xd = *(const float4*)(xp + 36);
        }
        f32x4 hid0 = b1a;
        hid0 = MFMA(aW1_00, xB0, hid0); hid0 = MFMA(aW1_01, xB1, hid0);
        f32x4 hid1 = b1b;
        hid1 = MFMA(aW1_10, xB0, hid1); hid1 = MFMA(aW1_11, xB1, hid1);
#pragma unroll
        for (int j = 0; j < 4; ++j) { hid0[j] = fmaxf(hid0[j], 0.f); hid1[j] = fmaxf(hid1[j], 0.f); }
        *(short4v*)(HIDb + sHidW0) = cvt4(hid0);
        *(short4v*)(HIDb + sHidW1) = cvt4(hid1);
      }
      barrier_lds();
      // ============== window C: xg_{t+1} ==============
      if (t + 1 < T_STEPS) {
        bf16x8 hdB0 = *(const bf16x8*)(HIDb + sHid0);
        bf16x8 hdB1 = *(const bf16x8*)(HIDb + sHid1);
        bf16x8 hdB2 = *(const bf16x8*)(HIDb + sHid2);
        bf16x8 hdB3 = *(const bf16x8*)(HIDb + sHid3);
        f32x4 xg = b2w;
        xg = MFMA(aW2_0, hdB0, xg); xg = MFMA(aW2_1, hdB1, xg);
        xg = MFMA(aW2_2, hdB2, xg); xg = MFMA(aW2_3, hdB3, xg);
        *(short4v*)(XGb + sW) = cvt4(xg);
      }
      barrier_lds();
    } else {
      // ============== P0 (window A): r,z from h ==============
      bf16x8 hB0h = *(const bf16x8*)(Hhi + sR0);
      bf16x8 hB1h = *(const bf16x8*)(Hhi + sR1);
      bf16x8 hB0l = *(const bf16x8*)(Hlo + sR0);
      bf16x8 hB1l = *(const bf16x8*)(Hlo + sR1);
      f32x4 rph = {0.f, 0.f, 0.f, 0.f}, rpl = {0.f, 0.f, 0.f, 0.f};
      rph = MFMA(aR0, hB0h, rph); rph = MFMA(aR1, hB1h, rph);
      rpl = MFMA(aR0, hB0l, rpl); rpl = MFMA(aR1, hB1l, rpl);
      f32x4 zph = {0.f, 0.f, 0.f, 0.f}, zpl = {0.f, 0.f, 0.f, 0.f};
      zph = MFMA(aZ0, hB0h, zph); zph = MFMA(aZ1, hB1h, zph);
      zpl = MFMA(aZ0, hB0l, zpl); zpl = MFMA(aZ1, hB1l, zpl);
      f32x4 rr = sigm4(rph + rpl);
      {
        short4v phi, plo; split4(rr * hreg, phi, plo);
        *(short4v*)(RHhi + sW) = phi;
        *(short4v*)(RHlo + sW) = plo;
      }
      f32x4 zz = sigm4(zph + zpl);  // after RH write: overlaps barrier wait
      barrier_lds();
      // ============== P1 (window B): u; ODE Euler ==============
      __builtin_amdgcn_s_setprio(1);
      bf16x8 rhB0h = *(const bf16x8*)(RHhi + sR0);
      bf16x8 rhB1h = *(const bf16x8*)(RHhi + sR1);
      bf16x8 rhB0l = *(const bf16x8*)(RHlo + sR0);
      bf16x8 rhB1l = *(const bf16x8*)(RHlo + sR1);
      f32x4 uph = {0.f, 0.f, 0.f, 0.f}, upl = {0.f, 0.f, 0.f, 0.f};
      uph = MFMA(aU0, rhB0h, uph); uph = MFMA(aU1, rhB1h, uph);
      upl = MFMA(aU0, rhB0l, upl); upl = MFMA(aU1, rhB1l, upl);
      f32x4 uu = tanh4(uph + upl);
      f32x4 hp = hreg + (1.f - zz) * (uu - hreg);  // ODE Euler step (DT=1)
      {
        short4v phi, plo; split4(hp, phi, plo);
        *(short4v*)(H2hi + sW) = phi;
        *(short4v*)(H2lo + sW) = plo;
      }
      barrier_lds();
      // ============== P2 (window C): GRU gates; h_new ==============
      bf16x8 h2B0h = *(const bf16x8*)(H2hi + sR0);
      bf16x8 h2B1h = *(const bf16x8*)(H2hi + sR1);
      bf16x8 h2B0l = *(const bf16x8*)(H2lo + sR0);
      bf16x8 h2B1l = *(const bf16x8*)(H2lo + sR1);
      f32x4 gir = *(const f32x4*)(GIb + 0 * 4096 + giR);
      f32x4 giz = *(const f32x4*)(GIb + 1 * 4096 + giR);
      f32x4 gin = *(const f32x4*)(GIb + 2 * 4096 + giR);

      f32x4 hrh = {0.f, 0.f, 0.f, 0.f}, hrl = {0.f, 0.f, 0.f, 0.f};
      hrh = MFMA(aHR0, h2B0h, hrh); hrh = MFMA(aHR1, h2B1h, hrh);
      hrl = MFMA(aHR0, h2B0l, hrl); hrl = MFMA(aHR1, h2B1l, hrl);
      f32x4 hzh = {0.f, 0.f, 0.f, 0.f}, hzl = {0.f, 0.f, 0.f, 0.f};
      hzh = MFMA(aHZ0, h2B0h, hzh); hzh = MFMA(aHZ1, h2B1h, hzh);
      hzl = MFMA(aHZ0, h2B0l, hzl); hzl = MFMA(aHZ1, h2B1l, hzl);
      f32x4 hnh = bhn, hnl = {0.f, 0.f, 0.f, 0.f};
      hnh = MFMA(aHN0, h2B0h, hnh); hnh = MFMA(aHN1, h2B1h, hnh);
      hnl = MFMA(aHN0, h2B0l, hnl); hnl = MFMA(aHN1, h2B1l, hnl);

      f32x4 r2 = sigm4(gir + hrh + hrl);
      f32x4 z2 = sigm4(giz + hzh + hzl);
      f32x4 nn = tanh4(gin + r2 * (hnh + hnl));
      hreg = (1.f - z2) * nn + z2 * hp;  // h_new
      {
        short4v phi, plo; split4(hreg, phi, plo);
        *(short4v*)(Hhi + sW) = phi;
        *(short4v*)(Hlo + sW) = plo;
      }
      __builtin_amdgcn_s_setprio(0);
      barrier_lds();
    }
  }

  // epilogue: output head for t = T-1 (Hhi/Hlo hold h_{T-1})
  if (helper && hw < 2) {
    bf16x8 hB0h = *(const bf16x8*)(Hhi + sR0);
    bf16x8 hB1h = *(const bf16x8*)(Hhi + sR1);
    bf16x8 hB0l = *(const bf16x8*)(Hlo + sR0);
    bf16x8 hB1l = *(const bf16x8*)(Hlo + sR1);
    f32x4 a5 = brw, a5l = {0.f, 0.f, 0.f, 0.f};
    a5 = MFMA(aWr0, hB0h, a5);   a5 = MFMA(aWr1, hB1h, a5);
    a5l = MFMA(aWr0, hB0l, a5l); a5l = MFMA(aWr1, hB1l, a5l);
    a5 += a5l;
    if (hw == 0 || g < 2) { outp[0] = a5[0]; outp[1] = a5[1]; outp[2] = a5[2]; outp[3] = a5[3]; }
  }
}

extern "C" void kernel_launch(void* const* d_in, const int* in_sizes, int n_in,
                              void* d_out, int out_size, void* d_ws, size_t ws_size,
                              hipStream_t stream) {
  (void)in_sizes; (void)n_in; (void)d_ws; (void)ws_size; (void)out_size;
  const float* H   = (const float*)d_in[0];
  // d_in[1] = times (unused: delta_t == 1 -> exactly one Euler step per observation)
  const float* W1  = (const float*)d_in[2];
  const float* b1  = (const float*)d_in[3];
  const float* W2  = (const float*)d_in[4];
  const float* b2  = (const float*)d_in[5];
  const float* Whr = (const float*)d_in[6];
  const float* Whz = (const float*)d_in[7];
  const float* Whh = (const float*)d_in[8];
  const float* wih = (const float*)d_in[9];
  const float* whh = (const float*)d_in[10];
  const float* bih = (const float*)d_in[11];
  const float* bhh = (const float*)d_in[12];
  const float* Wr  = (const float*)d_in[13];
  const float* br  = (const float*)d_in[14];
  float* out = (float*)d_out;

  odegru<<<dim3(2048 / 16), dim3(512), 0, stream>>>(
      H, W1, b1, W2, b2, Whr, Whz, Whh, wih, whh, bih, bhh, Wr, br, out);
}